// Round 8
// baseline (123.007 us; speedup 1.0000x reference)
//
#include <hip/hip_runtime.h>
#include <math.h>

#define WAVES_PER_BLOCK 4
#define BLOCK 256
#define DEPOS_PER_WAVE 8

typedef float f32x4 __attribute__((ext_vector_type(4)));
typedef float f32x2 __attribute__((ext_vector_type(2)));

__global__ __launch_bounds__(BLOCK) void raster_kernel(
    const float* __restrict__ sigma,    // [N,3]
    const float* __restrict__ time_,    // [N]
    const float* __restrict__ charge,   // [N]
    const float* __restrict__ tail,     // [N,3]
    const float* __restrict__ gsp,      // [3]
    float* __restrict__ out_r,          // [N,10,10,10]
    float* __restrict__ out_off,        // [N,3] written as float values
    int n)
{
    // per-wave scratch (no cross-wave sharing -> NO barriers anywhere)
    __shared__ float s_qw01[WAVES_PER_BLOCK][104];  // charge*w0[i0]*w1[i1] (+pad)
    __shared__ float s_w2e [WAVES_PER_BLOCK][16];   // w2 wrap: w2e[j]=w2[j%10], j<13

    const int wave = threadIdx.x >> 6;
    const int lane = threadIdx.x & 63;
    const int wid  = blockIdx.x * WAVES_PER_BLOCK + wave;

    // BLOCKED assignment at FULL occupancy: wave owns 8 consecutive depos.
    // Inputs for d..d+7 share cache lines -> depth-1 prefetch = L1 hit.
    // Output = 32 KB contiguous run per wave.
    int d = wid * DEPOS_PER_WAVE;
    const int dend = min(d + DEPOS_PER_WAVE, n);

    const float g0 = gsp[0], g1 = gsp[1], g2 = gsp[2];

    // lane roles (loop-invariant): lanes 0..10 dim0, 11..21 dim1, 22..32 dim2
    const int dim = lane / 11;            // 0..2 for lane<33
    const int k   = lane - dim * 11;      // 0..10
    const float gdim = (dim == 0) ? g0 : (dim == 1) ? g1 : g2;

    // A2 gather shuffle sources (loop-invariant):
    // w0[j] in lane j, w1[j] in lane 11+j, w2[j] in lane 22+j
    const int i0a = lane;
    const int s0a = i0a / 10, s1a = 11 + i0a % 10;
    const int i0b = lane + 64;
    const int s0b = i0b / 10, s1b = 11 + i0b % 10;

    // phase-B loop-invariant per-chunk indices: c = lane+64cc, f = 4c
    // i2 = f%10 always EVEN -> w2e reads are 8B-aligned f32x2 pairs;
    // decade crossing within a chunk only when i2 == 8 (elements z,w).
    int  jc[4], i2c[4];
    bool on[4], cross[4];
    #pragma unroll
    for (int cc = 0; cc < 4; ++cc) {
        int c = lane + 64 * cc;
        on[cc]    = (c < 250);
        int f     = 4 * c;
        jc[cc]    = f / 10;
        i2c[cc]   = f % 10;
        cross[cc] = (i2c[cc] == 8);
    }

    const float* qw  = s_qw01[wave];
    const float* w2e = s_w2e[wave];

    float pt = 0.f, sg = 1.f, q = 0.f;
    if (d < dend) {
        if (lane < 33) {
            pt = (dim == 0) ? tail[(size_t)d*3 + 1]
               : (dim == 1) ? tail[(size_t)d*3 + 2]
               : time_[d];
            sg = sigma[(size_t)d*3 + dim];
        }
        q = charge[d];
    }

    for (; d < dend; ++d) {
        const int dn = d + 1;

        // ---- phase A: 33 edge CDFs in lanes 0..32 ----
        float cdf = 0.0f, iminf = 0.0f;
        if (lane < 33) {
            iminf = floorf((pt - 3.0f * sg) / gdim);
            float edge = (iminf + (float)k) * gdim;
            float z = (edge - pt) / (sg * 1.4142135623730951f);
            cdf = 0.5f * (1.0f + erff(z));
        }
        float cdf1 = __shfl_down(cdf, 1);
        float wv = cdf1 - cdf;            // per-cell weight, valid where k<10

        if (lane < 33 && k == 0)
            out_off[(size_t)d*3 + dim] = iminf;

        // ---- prefetch next depo's inputs (sequential -> L1 hit) ----
        float npt = 0.f, nsg = 1.f, nq = 0.f;
        if (dn < dend) {
            if (lane < 33) {
                npt = (dim == 0) ? tail[(size_t)dn*3 + 1]
                    : (dim == 1) ? tail[(size_t)dn*3 + 2]
                    : time_[dn];
                nsg = sigma[(size_t)dn*3 + dim];
            }
            nq = charge[dn];
        }

        // ---- phase A2: qw01 table + w2 wrap table (wave-local) ----
        {
            float w0a = __shfl(wv, s0a);
            float w1a = __shfl(wv, s1a);
            s_qw01[wave][i0a] = q * w0a * w1a;
            float w0b = __shfl(wv, s0b);
            float w1b = __shfl(wv, s1b);
            if (i0b < 100) s_qw01[wave][i0b] = q * w0b * w1b;
            if (lane >= 22 && lane < 32) s_w2e[wave][lane - 22] = wv;
            if (lane >= 22 && lane < 25) s_w2e[wave][lane - 22 + 10] = wv;
        }
        // same-wave DS ops are in-order; no __syncthreads needed (per-wave data)

        // ---- phase B: 250 f32x4 stores, merged DS reads ----
        {
            float* base = out_r + (size_t)d * 1000;
            #pragma unroll
            for (int cc = 0; cc < 4; ++cc) {
                if (on[cc]) {
                    float a = qw[jc[cc]];
                    float b = qw[jc[cc] + 1];          // only used when cross
                    f32x2 wlo = *reinterpret_cast<const f32x2*>(&w2e[i2c[cc]]);
                    f32x2 whi = *reinterpret_cast<const f32x2*>(&w2e[i2c[cc] + 2]);
                    float qzw = cross[cc] ? b : a;
                    f32x4 v;
                    v.x = a   * wlo.x;
                    v.y = a   * wlo.y;
                    v.z = qzw * whi.x;
                    v.w = qzw * whi.y;
                    *reinterpret_cast<f32x4*>(base + 4 * (lane + 64 * cc)) = v;
                }
            }
        }

        pt = npt; sg = nsg; q = nq;
    }
}

extern "C" void kernel_launch(void* const* d_in, const int* in_sizes, int n_in,
                              void* d_out, int out_size, void* d_ws, size_t ws_size,
                              hipStream_t stream) {
    const float* sigma  = (const float*)d_in[0];
    const float* time_  = (const float*)d_in[1];
    const float* charge = (const float*)d_in[2];
    const float* tail   = (const float*)d_in[3];
    const float* gsp    = (const float*)d_in[4];

    const int n = in_sizes[1];          // N depos (time is [N])
    float* out_r   = (float*)d_out;
    float* out_off = out_r + (size_t)n * 1000;

    // Full occupancy (4096 blocks, R3's best) + blocked 8-depo runs per wave:
    // isolates input/output locality from occupancy (R6 confounded them).
    const int nwaves = (n + DEPOS_PER_WAVE - 1) / DEPOS_PER_WAVE;   // 16384
    const int blocks = (nwaves + WAVES_PER_BLOCK - 1) / WAVES_PER_BLOCK;

    raster_kernel<<<blocks, BLOCK, 0, stream>>>(sigma, time_, charge, tail, gsp,
                                                out_r, out_off, n);
}

// Round 9
// 114.181 us; speedup vs baseline: 1.0773x; 1.0773x over previous
//
#include <hip/hip_runtime.h>
#include <math.h>

#define WAVES_PER_BLOCK 4
#define BLOCK 256

typedef float f32x4 __attribute__((ext_vector_type(4)));
typedef float f32x2 __attribute__((ext_vector_type(2)));

__global__ __launch_bounds__(BLOCK) void raster_kernel(
    const float* __restrict__ sigma,    // [N,3]
    const float* __restrict__ time_,    // [N]
    const float* __restrict__ charge,   // [N]
    const float* __restrict__ tail,     // [N,3]
    const float* __restrict__ gsp,      // [3]
    float* __restrict__ out_r,          // [N,10,10,10]
    float* __restrict__ out_off,        // [N,3] written as float values
    int n, int niter2)
{
    // per-wave scratch, two depo slots (A/B) -> no barriers anywhere
    __shared__ float s_qw01[WAVES_PER_BLOCK][2][104];
    __shared__ float s_w2e [WAVES_PER_BLOCK][2][16];

    const int wave = threadIdx.x >> 6;
    const int lane = threadIdx.x & 63;
    const int nwaves = gridDim.x * WAVES_PER_BLOCK;
    int d = blockIdx.x * WAVES_PER_BLOCK + wave;

    const float g0 = gsp[0], g1 = gsp[1], g2 = gsp[2];

    // lane roles (loop-invariant): lanes 0..10 dim0, 11..21 dim1, 22..32 dim2
    const int dim = lane / 11;
    const int k   = lane - dim * 11;
    const float gdim = (dim == 0) ? g0 : (dim == 1) ? g1 : g2;

    // A2 gather shuffle sources: w0[j] in lane j, w1[j] in lane 11+j, w2[j] in 22+j
    const int i0a = lane;
    const int s0a = i0a / 10, s1a = 11 + i0a % 10;
    const int i0b = lane + 64;
    const int s0b = i0b / 10, s1b = 11 + i0b % 10;

    // phase-B loop-invariant chunk indices: c = lane+64cc, f = 4c
    int  jc[4], i2c[4];
    bool on[4], cross[4];
    #pragma unroll
    for (int cc = 0; cc < 4; ++cc) {
        int c = lane + 64 * cc;
        on[cc]    = (c < 250);
        int f     = 4 * c;
        jc[cc]    = f / 10;
        i2c[cc]   = f % 10;
        cross[cc] = (i2c[cc] == 8);
    }

    const float* qwA  = s_qw01[wave][0];
    const float* qwB  = s_qw01[wave][1];
    const float* w2eA = s_w2e[wave][0];
    const float* w2eB = s_w2e[wave][1];

    for (int it = 0; it < niter2; ++it, d += 2 * nwaves) {
        const int dA = d, dB = d + nwaves;
        const bool actA = (dA < n), actB = (dB < n);

        // ---- inputs for both depos (independent loads, overlapped) ----
        float ptA = 0.f, sgA = 1.f, qA = 0.f;
        float ptB = 0.f, sgB = 1.f, qB = 0.f;
        if (actA) {
            if (lane < 33) {
                ptA = (dim == 0) ? tail[(size_t)dA*3 + 1]
                    : (dim == 1) ? tail[(size_t)dA*3 + 2]
                    : time_[dA];
                sgA = sigma[(size_t)dA*3 + dim];
            }
            qA = charge[dA];
        }
        if (actB) {
            if (lane < 33) {
                ptB = (dim == 0) ? tail[(size_t)dB*3 + 1]
                    : (dim == 1) ? tail[(size_t)dB*3 + 2]
                    : time_[dB];
                sgB = sigma[(size_t)dB*3 + dim];
            }
            qB = charge[dB];
        }

        // ---- phase A: two interleaved erf chains (2x ILP) ----
        float cdfA = 0.f, iminfA = 0.f, cdfB = 0.f, iminfB = 0.f;
        if (lane < 33) {
            iminfA = floorf((ptA - 3.0f * sgA) / gdim);
            iminfB = floorf((ptB - 3.0f * sgB) / gdim);
            float edgeA = (iminfA + (float)k) * gdim;
            float edgeB = (iminfB + (float)k) * gdim;
            float zA = (edgeA - ptA) / (sgA * 1.4142135623730951f);
            float zB = (edgeB - ptB) / (sgB * 1.4142135623730951f);
            cdfA = 0.5f * (1.0f + erff(zA));
            cdfB = 0.5f * (1.0f + erff(zB));
        }
        float cdf1A = __shfl_down(cdfA, 1);
        float cdf1B = __shfl_down(cdfB, 1);
        float wvA = cdf1A - cdfA;
        float wvB = cdf1B - cdfB;

        if (lane < 33 && k == 0) {
            if (actA) out_off[(size_t)dA*3 + dim] = iminfA;
            if (actB) out_off[(size_t)dB*3 + dim] = iminfB;
        }

        // ---- phase A2: build both tables (wave-local, in-order DS) ----
        {
            float w0aA = __shfl(wvA, s0a), w1aA = __shfl(wvA, s1a);
            float w0aB = __shfl(wvB, s0a), w1aB = __shfl(wvB, s1a);
            s_qw01[wave][0][i0a] = qA * w0aA * w1aA;
            s_qw01[wave][1][i0a] = qB * w0aB * w1aB;
            float w0bA = __shfl(wvA, s0b), w1bA = __shfl(wvA, s1b);
            float w0bB = __shfl(wvB, s0b), w1bB = __shfl(wvB, s1b);
            if (i0b < 100) {
                s_qw01[wave][0][i0b] = qA * w0bA * w1bA;
                s_qw01[wave][1][i0b] = qB * w0bB * w1bB;
            }
            if (lane >= 22 && lane < 32) {
                s_w2e[wave][0][lane - 22] = wvA;
                s_w2e[wave][1][lane - 22] = wvB;
            }
            if (lane >= 22 && lane < 25) {
                s_w2e[wave][0][lane - 22 + 10] = wvA;
                s_w2e[wave][1][lane - 22 + 10] = wvB;
            }
        }

        // ---- phase B: 32 stores from distinct reg sets (2x pipeline depth) ----
        if (actA) {
            float* base = out_r + (size_t)dA * 1000;
            #pragma unroll
            for (int cc = 0; cc < 4; ++cc) {
                if (on[cc]) {
                    float a = qwA[jc[cc]];
                    float b = qwA[jc[cc] + 1];
                    f32x2 wlo = *reinterpret_cast<const f32x2*>(&w2eA[i2c[cc]]);
                    f32x2 whi = *reinterpret_cast<const f32x2*>(&w2eA[i2c[cc] + 2]);
                    float qzw = cross[cc] ? b : a;
                    f32x4 v;
                    v.x = a   * wlo.x;
                    v.y = a   * wlo.y;
                    v.z = qzw * whi.x;
                    v.w = qzw * whi.y;
                    *reinterpret_cast<f32x4*>(base + 4 * (lane + 64 * cc)) = v;
                }
            }
        }
        if (actB) {
            float* base = out_r + (size_t)dB * 1000;
            #pragma unroll
            for (int cc = 0; cc < 4; ++cc) {
                if (on[cc]) {
                    float a = qwB[jc[cc]];
                    float b = qwB[jc[cc] + 1];
                    f32x2 wlo = *reinterpret_cast<const f32x2*>(&w2eB[i2c[cc]]);
                    f32x2 whi = *reinterpret_cast<const f32x2*>(&w2eB[i2c[cc] + 2]);
                    float qzw = cross[cc] ? b : a;
                    f32x4 v;
                    v.x = a   * wlo.x;
                    v.y = a   * wlo.y;
                    v.z = qzw * whi.x;
                    v.w = qzw * whi.y;
                    *reinterpret_cast<f32x4*>(base + 4 * (lane + 64 * cc)) = v;
                }
            }
        }
    }
}

extern "C" void kernel_launch(void* const* d_in, const int* in_sizes, int n_in,
                              void* d_out, int out_size, void* d_ws, size_t ws_size,
                              hipStream_t stream) {
    const float* sigma  = (const float*)d_in[0];
    const float* time_  = (const float*)d_in[1];
    const float* charge = (const float*)d_in[2];
    const float* tail   = (const float*)d_in[3];
    const float* gsp    = (const float*)d_in[4];

    const int n = in_sizes[1];          // N depos (time is [N])
    float* out_r   = (float*)d_out;
    float* out_off = out_r + (size_t)n * 1000;

    const int blocks = 4096;            // R3's best config, grid-stride
    const int nwaves = blocks * WAVES_PER_BLOCK;        // 16384
    const int niter  = (n + nwaves - 1) / nwaves;       // 8 at N=131072
    const int niter2 = (niter + 1) / 2;                 // unroll-2

    raster_kernel<<<blocks, BLOCK, 0, stream>>>(sigma, time_, charge, tail, gsp,
                                                out_r, out_off, n, niter2);
}